// Round 4
// baseline (81.446 us; speedup 1.0000x reference)
//
#include <hip/hip_runtime.h>

#define N_ATOMS 8388608
#define N_MOLS  262144
#define TPB 256
#define APT 4
#define TILE (TPB * APT)          // 1024 atoms per block
#define NBLK (N_ATOMS / TILE)     // 8192 blocks
#define MAXBINS (TILE + 64)       // slack for (rare) empty-molecule id gaps

// Pass 1: block-local binned segment sum.
// - 4 atoms/thread: q/mol loads are lane-contiguous dwordx4 (fully coalesced),
//   h is 2 dwordx4 at 32B lane stride (2x line cost, h only).
// - per-thread serial accumulate over its 4 contiguous atoms, flushing each
//   molecule's partial into an LDS bin via ds-atomic (no shuffle scan).
// - write-out: molecules strictly inside the block's id range are PLAIN
//   stores (exactly one block owns them, since mol_id is sorted); only the
//   two boundary molecules use global atomics (~50K atomics total).
__global__ __launch_bounds__(TPB) void ce_pass1(
    const float4* __restrict__ h4, const float4* __restrict__ q4,
    const int4* __restrict__ mol4,
    float* __restrict__ sum_q, float* __restrict__ sum_si,
    float* __restrict__ sum_esi)
{
    __shared__ float bq[MAXBINS], bs[MAXBINS], be[MAXBINS];
    __shared__ int shFirst, shLast;

    const int t = threadIdx.x;
    const int base = blockIdx.x * TILE;

    // issue global loads first so they overlap the bin zeroing
    int4   m4 = mol4[base / 4 + t];
    float4 qv = q4[base / 4 + t];
    float4 hA = h4[base / 2 + t * 2];
    float4 hB = h4[base / 2 + t * 2 + 1];

    for (int i = t; i < MAXBINS; i += TPB) { bq[i] = 0.f; bs[i] = 0.f; be[i] = 0.f; }
    if (t == 0)       shFirst = m4.x;
    if (t == TPB - 1) shLast  = m4.w;
    __syncthreads();

    const int molFirst = shFirst;
    const int molLast  = shLast;

    float e[4]  = {hA.x, hA.z, hB.x, hB.z};
    float s[4]  = {hA.y, hA.w, hB.y, hB.w};
    float qq[4] = {qv.x, qv.y, qv.z, qv.w};
    int   mm[4] = {m4.x, m4.y, m4.z, m4.w};

    auto flush = [&](int m, float aq, float as, float ae) {
        int bin = m - molFirst;
        if (bin < MAXBINS) {
            atomicAdd(&bq[bin], aq);
            atomicAdd(&bs[bin], as);
            atomicAdd(&be[bin], ae);
        } else {  // id gap overflow (rare): go straight to global
            atomicAdd(&sum_q[m], aq);
            atomicAdd(&sum_si[m], as);
            atomicAdd(&sum_esi[m], ae);
        }
    };

    int mcur = mm[0];
    float aq = 0.f, as = 0.f, ae = 0.f;
    #pragma unroll
    for (int k = 0; k < 4; ++k) {
        float si = 1.0f / s[k];
        if (mm[k] != mcur) {
            flush(mcur, aq, as, ae);
            mcur = mm[k]; aq = 0.f; as = 0.f; ae = 0.f;
        }
        aq += qq[k]; as += si; ae += e[k] * si;
    }
    flush(mcur, aq, as, ae);
    __syncthreads();

    // write-out
    int range = molLast - molFirst + 1;
    int n = range < MAXBINS ? range : MAXBINS;
    for (int i = t; i < n; i += TPB) {
        int m = molFirst + i;
        float vq = bq[i], vs = bs[i], ve = be[i];
        if (i == 0 || m == molLast) {
            if (vs != 0.f) {
                atomicAdd(&sum_q[m], vq);
                atomicAdd(&sum_si[m], vs);
                atomicAdd(&sum_esi[m], ve);
            }
        } else {
            sum_q[m] = vq; sum_si[m] = vs; sum_esi[m] = ve;
        }
    }
}

// Pass 2: per-molecule combine: t = (sum_q + sum_esi) / sum_si
__global__ __launch_bounds__(TPB) void ce_pass2(
    const float* __restrict__ sum_q, const float* __restrict__ sum_si,
    const float* __restrict__ sum_esi, float* __restrict__ t)
{
    int m = blockIdx.x * blockDim.x + threadIdx.x;
    t[m] = (sum_q[m] + sum_esi[m]) / sum_si[m];
}

// Pass 3: 4 atoms/thread, coalesced mol/out, h at 32B lane stride.
__global__ __launch_bounds__(TPB) void ce_pass3(
    const float4* __restrict__ h4, const int4* __restrict__ mol4,
    const float* __restrict__ tmol, float4* __restrict__ out4)
{
    int g = blockIdx.x * TPB + threadIdx.x;   // over N_ATOMS/4
    int4   m4 = mol4[g];
    float4 hA = h4[g * 2];
    float4 hB = h4[g * 2 + 1];
    float4 o;
    o.x = (tmol[m4.x] - hA.x) / hA.y;
    o.y = (tmol[m4.y] - hA.z) / hA.w;
    o.z = (tmol[m4.z] - hB.x) / hB.y;
    o.w = (tmol[m4.w] - hB.z) / hB.w;
    out4[g] = o;
}

extern "C" void kernel_launch(void* const* d_in, const int* in_sizes, int n_in,
                              void* d_out, int out_size, void* d_ws, size_t ws_size,
                              hipStream_t stream) {
    const float4* h4   = (const float4*)d_in[0];
    const float4* q4   = (const float4*)d_in[1];
    const int4*   mol4 = (const int4*)d_in[2];
    float4* out4 = (float4*)d_out;

    float* sum_q   = (float*)d_ws;
    float* sum_si  = sum_q  + N_MOLS;
    float* sum_esi = sum_si + N_MOLS;
    float* t       = sum_esi + N_MOLS;

    hipMemsetAsync(d_ws, 0, (size_t)3 * N_MOLS * sizeof(float), stream);

    ce_pass1<<<NBLK, TPB, 0, stream>>>(h4, q4, mol4, sum_q, sum_si, sum_esi);
    ce_pass2<<<N_MOLS / TPB, TPB, 0, stream>>>(sum_q, sum_si, sum_esi, t);
    ce_pass3<<<N_ATOMS / 4 / TPB, TPB, 0, stream>>>(h4, mol4, t, out4);
}